// Round 9
// baseline (1000.057 us; speedup 1.0000x reference)
//
#include <hip/hip_runtime.h>
#include <hip/hip_bf16.h>
#include <math.h>

// Problem constants
#define HH 128
#define WWW 128
#define BB 8
#define MM (HH*WWW*BB)      // 131072 rows (h,w,b)

typedef unsigned int u32;
typedef unsigned short u16;

__device__ __forceinline__ float b2f(u16 s){ return __uint_as_float(((u32)s)<<16); }
__device__ __forceinline__ u16 f2b(float f){
    u32 u = __float_as_uint(f);
    return (u16)((u + 0x7fffu + ((u>>16)&1u)) >> 16);
}
__device__ __forceinline__ u32 pack2(float lo, float hi){
    return (u32)f2b(lo) | ((u32)f2b(hi)<<16);
}

// ---------------- K0: trig tables only --------------------------------------
__global__ __launch_bounds__(128) void k_prep(const float* __restrict__ th_f,
                                              const float* __restrict__ th_r,
                                              float* __restrict__ trig)
{
    int d = threadIdx.x;          // 128 threads, 1 block
    trig[d]     = cosf(th_f[d]); trig[128+d] = sinf(th_f[d]);
    trig[256+d] = cosf(th_r[d]); trig[384+d] = sinf(th_r[d]);
}

// ---------------- K1: fused front: inp + lambda + gate, F32 compute ---------
// 10 chunks of 64 cols: 0-3 inp -> SC bf16 (d_out); 4-5 lam -> OM bf16 (ws);
// 6-9 gate -> GATE bf16 (ws). x staged once. Proven 4x4 f32 chunk structure.
__global__ __launch_bounds__(256) void k_front(
    const float* __restrict__ x,
    const float* __restrict__ W_in,   const float* __restrict__ b_in,
    const float* __restrict__ W_lam,  const float* __restrict__ b_lam,
    const float* __restrict__ W_gate, const float* __restrict__ b_gate,
    u16* __restrict__ SC, u16* __restrict__ OM, u16* __restrict__ GATE)
{
    __shared__ float xs_t[128][64];   // 32 KiB  [k][r]
    __shared__ float wt[128][64];     // 32 KiB  [k][c]
    int tid = threadIdx.x;
    int m0 = blockIdx.x * 64;         // 2048 blocks

    #pragma unroll
    for (int it = 0; it < 8; ++it) {  // stage x transposed: 64 rows x 128 k
        int u = it*256 + tid;
        int r = u >> 5, c4 = u & 31;
        float4 v = *(const float4*)(x + (size_t)(m0+r)*128 + c4*4);
        xs_t[c4*4+0][r] = v.x; xs_t[c4*4+1][r] = v.y;
        xs_t[c4*4+2][r] = v.z; xs_t[c4*4+3][r] = v.w;
    }

    int ri = tid >> 4, ci = tid & 15;

    for (int nc = 0; nc < 10; ++nc) {
        __syncthreads();
        #pragma unroll
        for (int it = 0; it < 32; ++it) {     // stage W chunk: 128k x 64c
            int u = it*256 + tid;
            int k = u >> 6, c = u & 63;
            wt[k][c] = (nc < 4) ? W_in[k*256 + nc*64 + c]
                     : (nc < 6) ? W_lam[k*128 + (nc-4)*64 + c]
                                : W_gate[k*256 + (nc-6)*64 + c];
        }
        __syncthreads();

        float acc[4][4] = {};
        #pragma unroll 8
        for (int k = 0; k < 128; ++k) {
            float4 xv = *(const float4*)(&xs_t[k][ri*4]);
            float4 wv = *(const float4*)(&wt[k][ci*4]);
            acc[0][0] = fmaf(xv.x, wv.x, acc[0][0]);
            acc[0][1] = fmaf(xv.x, wv.y, acc[0][1]);
            acc[0][2] = fmaf(xv.x, wv.z, acc[0][2]);
            acc[0][3] = fmaf(xv.x, wv.w, acc[0][3]);
            acc[1][0] = fmaf(xv.y, wv.x, acc[1][0]);
            acc[1][1] = fmaf(xv.y, wv.y, acc[1][1]);
            acc[1][2] = fmaf(xv.y, wv.z, acc[1][2]);
            acc[1][3] = fmaf(xv.y, wv.w, acc[1][3]);
            acc[2][0] = fmaf(xv.z, wv.x, acc[2][0]);
            acc[2][1] = fmaf(xv.z, wv.y, acc[2][1]);
            acc[2][2] = fmaf(xv.z, wv.z, acc[2][2]);
            acc[2][3] = fmaf(xv.z, wv.w, acc[2][3]);
            acc[3][0] = fmaf(xv.w, wv.x, acc[3][0]);
            acc[3][1] = fmaf(xv.w, wv.y, acc[3][1]);
            acc[3][2] = fmaf(xv.w, wv.z, acc[3][2]);
            acc[3][3] = fmaf(xv.w, wv.w, acc[3][3]);
        }

        #pragma unroll
        for (int i = 0; i < 4; ++i) {
            int m = m0 + ri*4 + i;
            float v[4];
            #pragma unroll
            for (int j = 0; j < 4; ++j) {
                int cc = ci*4 + j;
                float b = (nc < 4) ? b_in[nc*64 + cc]
                        : (nc < 6) ? b_lam[(nc-4)*64 + cc]
                                   : b_gate[(nc-6)*64 + cc];
                float t = acc[i][j] + b;
                float e = __expf(-t);
                v[j] = (nc >= 4 && nc < 6) ? e/(1.f+e)    // om = 1-sigmoid
                                           : t/(1.f+e);    // silu
            }
            uint2 pk = make_uint2(pack2(v[0], v[1]), pack2(v[2], v[3]));
            if (nc < 4)
                *(uint2*)(&SC[(size_t)m*256 + nc*64 + ci*4]) = pk;
            else if (nc < 6)
                *(uint2*)(&OM[(size_t)m*128 + (nc-4)*64 + ci*4]) = pk;
            else
                *(uint2*)(&GATE[(size_t)m*256 + (nc-6)*64 + ci*4]) = pk;
        }
    }
}

// ---------------- K2: fused fwd+rev complex scans, full-d, bf16 I/O ----------
// One thread runs BOTH directions of one column (2 independent chains).
// FIRSTPAIR=1 (h-axis): t<64 stores hit disjoint positions (fwd t vs rev
// 127-t); t>=64 RMW-adds positions this thread already wrote. FIRSTPAIR=0
// (w-axis): P holds h-results -> all RMW. P is packed bf16 (u32).
template<int AXISW, int FIRSTPAIR>
__global__ __launch_bounds__(256) void k_scan2(const u16* __restrict__ SC,
                                               const u16* __restrict__ OM,
                                               const float* __restrict__ trig,
                                               u32* P)
{
    int j = blockIdx.x*256 + threadIdx.x;  // 131072 columns (full d)
    int d = j & 127;
    int col = j >> 7;                      // 0..1023
    int rowbase, stride;
    if (AXISW) { rowbase = (col>>3)*1024 + (col&7); stride = 8; }
    else       { rowbase = col;                     stride = 1024; }

    float cfF = trig[d],     sfF = trig[128+d];
    float cfR = trig[256+d], sfR = trig[384+d];

    long long rowF = rowbase;
    long long rowR = (long long)rowbase + (long long)stride*127;

    float hfr=0.f, hfi=0.f, hrr=0.f, hri=0.f;

    #define SCAN_STEP                                                     \
        u32 uF = *(const u32*)(SC + rowF*256 + 2*d);                      \
        float omF = b2f(OM[rowF*128 + d]);                                \
        u32 uR = *(const u32*)(SC + rowR*256 + 2*d);                      \
        float omR = b2f(OM[rowR*128 + d]);                                \
        float lamF = 1.f - omF, lamR = 1.f - omR;                         \
        float grF = lamF*cfF, giF = lamF*sfF;                             \
        float grR = lamR*cfR, giR = lamR*sfR;                             \
        float ieF = b2f((u16)(uF & 0xffff)), ioF = b2f((u16)(uF >> 16));  \
        float ieR = b2f((u16)(uR & 0xffff)), ioR = b2f((u16)(uR >> 16));  \
        float nfr = fmaf(grF, hfr, fmaf(-giF, hfi, omF*ieF));             \
        float nfi = fmaf(grF, hfi, fmaf( giF, hfr, omF*ioF));             \
        hfr = nfr; hfi = nfi;                                             \
        float nrr = fmaf(grR, hrr, fmaf(-giR, hri, omR*ieR));             \
        float nri = fmaf(grR, hri, fmaf( giR, hrr, omR*ioR));             \
        hrr = nrr; hri = nri;                                             \
        long long piF = rowF*128 + d;                                     \
        long long piR = rowR*128 + d;

    if (FIRSTPAIR) {
        #pragma unroll 4
        for (int t = 0; t < 64; ++t, rowF += stride, rowR -= stride) {
            SCAN_STEP
            P[piF] = pack2(hfr, hfi);
            P[piR] = pack2(hrr, hri);
        }
        #pragma unroll 4
        for (int t = 64; t < 128; ++t, rowF += stride, rowR -= stride) {
            SCAN_STEP
            u32 oF = P[piF];
            P[piF] = pack2(b2f((u16)(oF&0xffff)) + hfr, b2f((u16)(oF>>16)) + hfi);
            u32 oR = P[piR];
            P[piR] = pack2(b2f((u16)(oR&0xffff)) + hrr, b2f((u16)(oR>>16)) + hri);
        }
    } else {
        #pragma unroll 4
        for (int t = 0; t < 128; ++t, rowF += stride, rowR -= stride) {
            SCAN_STEP
            u32 oF = P[piF];
            P[piF] = pack2(b2f((u16)(oF&0xffff)) + hfr, b2f((u16)(oF>>16)) + hfi);
            u32 oR = P[piR];
            P[piR] = pack2(b2f((u16)(oR&0xffff)) + hrr, b2f((u16)(oR>>16)) + hri);
        }
    }
    #undef SCAN_STEP
}

// ---------------- K3: LN + gate + out GEMM; bf16 fgT, 4x8 tiles -------------
#define GETC(v,i) ((i)==0?(v).x:(i)==1?(v).y:(i)==2?(v).z:(v).w)
__global__ __launch_bounds__(256, 4) void k_backend_f32(
    const uint4* __restrict__ P4, const u16* __restrict__ GATE,
    const float* __restrict__ W_out, const float* __restrict__ ln_w,
    const float* __restrict__ ln_b, const float* __restrict__ bo,
    float* __restrict__ out)
{
    __shared__ u16 fgT[256][68];                // 34 KiB bf16, [channel][row]
    int tid = threadIdx.x;
    int m0 = blockIdx.x * 64;                   // 2048 blocks
    int r = tid >> 2, q = tid & 3;              // 4 threads per row
    size_t prow4 = (size_t)(m0 + r)*32 + q*8;   // uint4 units (128 u32/row)
    size_t grow = (size_t)(m0 + r)*256;         // u16 units (GATE in ws)

    // gate, natural order: gate[pd] real, gate[128+pd] imag
    uint4 ga[4], gb[4];
    #pragma unroll
    for (int g4 = 0; g4 < 4; ++g4) {
        ga[g4] = *(const uint4*)(GATE + grow + q*32 + g4*8);
        gb[g4] = *(const uint4*)(GATE + grow + 128 + q*32 + g4*8);
    }

    uint4 pw[8];                                // 32 packed complex (bf16)
    #pragma unroll
    for (int c4 = 0; c4 < 8; ++c4) pw[c4] = P4[prow4 + c4];

    float fr_[32], fi_[32];
    #pragma unroll
    for (int c4 = 0; c4 < 8; ++c4) {
        #pragma unroll
        for (int w = 0; w < 4; ++w) {
            u32 word = GETC(pw[c4], w);
            int jj = c4*4 + w;
            fr_[jj] = b2f((u16)(word & 0xffff));
            fi_[jj] = b2f((u16)(word >> 16));
        }
    }

    float sum = 0.f, ss = 0.f;
    #pragma unroll
    for (int jj = 0; jj < 32; ++jj) {
        sum += fr_[jj] + fi_[jj];
        ss  += fr_[jj]*fr_[jj] + fi_[jj]*fi_[jj];
    }
    sum += __shfl_xor(sum, 1); sum += __shfl_xor(sum, 2);
    ss  += __shfl_xor(ss, 1);  ss  += __shfl_xor(ss, 2);
    float mu = sum * (1.f/256.f);
    float var = ss * (1.f/256.f) - mu*mu;
    float rstd = rsqrtf(var + 1e-5f);

    #pragma unroll
    for (int jj = 0; jj < 32; ++jj) {
        int pd = q*32 + jj;                     // complex channel 0..127
        int g4 = jj >> 3, e = jj & 7;
        u32 gur = GETC(ga[g4], e>>1), gui = GETC(gb[g4], e>>1);
        float gvr = b2f((u16)((e&1) ? (gur>>16) : (gur&0xffff)));
        float gvi = b2f((u16)((e&1) ? (gui>>16) : (gui&0xffff)));
        float vr = ((fr_[jj] - mu)*rstd*ln_w[pd]     + ln_b[pd])     * gvr;
        float vi = ((fi_[jj] - mu)*rstd*ln_w[128+pd] + ln_b[128+pd]) * gvi;
        fgT[pd][r]     = f2b(vr);
        fgT[128+pd][r] = f2b(vi);
    }
    __syncthreads();

    // out[64][128] = fgT^T @ W_out : 4m x 8n per thread, single pass
    int ri = tid >> 4, ci = tid & 15;
    float acc[4][8] = {};
    #pragma unroll 4
    for (int k = 0; k < 256; ++k) {
        uint2 xr = *(const uint2*)(&fgT[k][ri*4]);
        float xv0 = b2f((u16)(xr.x & 0xffff));
        float xv1 = b2f((u16)(xr.x >> 16));
        float xv2 = b2f((u16)(xr.y & 0xffff));
        float xv3 = b2f((u16)(xr.y >> 16));
        const float* wrow = W_out + (size_t)k*128 + ci*8;
        float4 wv0 = *(const float4*)(wrow);
        float4 wv1 = *(const float4*)(wrow + 4);
        #define FMA8(i, xv)                                    \
            acc[i][0] = fmaf(xv, wv0.x, acc[i][0]);            \
            acc[i][1] = fmaf(xv, wv0.y, acc[i][1]);            \
            acc[i][2] = fmaf(xv, wv0.z, acc[i][2]);            \
            acc[i][3] = fmaf(xv, wv0.w, acc[i][3]);            \
            acc[i][4] = fmaf(xv, wv1.x, acc[i][4]);            \
            acc[i][5] = fmaf(xv, wv1.y, acc[i][5]);            \
            acc[i][6] = fmaf(xv, wv1.z, acc[i][6]);            \
            acc[i][7] = fmaf(xv, wv1.w, acc[i][7]);
        FMA8(0, xv0) FMA8(1, xv1) FMA8(2, xv2) FMA8(3, xv3)
        #undef FMA8
    }
    #pragma unroll
    for (int i = 0; i < 4; ++i) {
        int m = m0 + ri*4 + i;
        #pragma unroll
        for (int j = 0; j < 8; ++j) {
            int n = ci*8 + j;
            out[(size_t)m*128 + n] = acc[i][j] + bo[n];
        }
    }
}

// ---------------- launch -----------------------------------------------------
extern "C" void kernel_launch(void* const* d_in, const int* in_sizes, int n_in,
                              void* d_out, int out_size, void* d_ws, size_t ws_size,
                              hipStream_t stream)
{
    const float* x      = (const float*)d_in[0];
    const float* W_in   = (const float*)d_in[1];
    const float* b_in   = (const float*)d_in[2];
    const float* W_lam  = (const float*)d_in[3];
    const float* b_lam  = (const float*)d_in[4];
    const float* th_f   = (const float*)d_in[5];
    const float* th_r   = (const float*)d_in[6];
    const float* W_gate = (const float*)d_in[7];
    const float* b_gate = (const float*)d_in[8];
    const float* W_out  = (const float*)d_in[9];
    const float* b_out  = (const float*)d_in[10];
    const float* ln_w   = (const float*)d_in[11];
    const float* ln_b   = (const float*)d_in[12];

    // ws layout: 167,774,208 B <= proven-safe envelope
    char* ws = (char*)d_ws;
    u32* P     = (u32*)(ws);                      //  67,108,864 (bf16-pair, full d)
    u16* OM    = (u16*)(ws + 67108864LL);         //  33,554,432 (bf16 om, full d)
    u16* GATE  = (u16*)(ws + 100663296LL);        //  67,108,864 (bf16 gate)
    float* trig= (float*)(ws + 167772160LL);      //   2,048

    // d_out time-shares: SC bf16[M][256] (front->scans) -> out f32[M][128]
    u16* SC   = (u16*)d_out;
    float* out = (float*)d_out;

    hipLaunchKernelGGL(k_prep, dim3(1), dim3(128), 0, stream, th_f, th_r, trig);

    hipLaunchKernelGGL(k_front, dim3(2048), dim3(256), 0, stream,
                       x, W_in, b_in, W_lam, b_lam, W_gate, b_gate,
                       SC, OM, GATE);

    hipLaunchKernelGGL(HIP_KERNEL_NAME(k_scan2<0,1>), dim3(512), dim3(256), 0, stream,
                       SC, OM, trig, P);
    hipLaunchKernelGGL(HIP_KERNEL_NAME(k_scan2<1,0>), dim3(512), dim3(256), 0, stream,
                       SC, OM, trig, P);

    hipLaunchKernelGGL(k_backend_f32, dim3(2048), dim3(256), 0, stream,
                       (const uint4*)P, GATE, W_out, ln_w, ln_b, b_out, out);
}

// Round 10
// 658.208 us; speedup vs baseline: 1.5194x; 1.5194x over previous
//
#include <hip/hip_runtime.h>
#include <hip/hip_bf16.h>
#include <math.h>

// Problem constants
#define HH 128
#define WWW 128
#define BB 8
#define MM (HH*WWW*BB)      // 131072 rows (h,w,b)

typedef unsigned int u32;
typedef unsigned short u16;

__device__ __forceinline__ float b2f(u16 s){ return __uint_as_float(((u32)s)<<16); }
__device__ __forceinline__ u16 f2b(float f){
    u32 u = __float_as_uint(f);
    return (u16)((u + 0x7fffu + ((u>>16)&1u)) >> 16);
}
__device__ __forceinline__ u32 pack2(float lo, float hi){
    return (u32)f2b(lo) | ((u32)f2b(hi)<<16);
}

// ---------------- K0: trig tables only --------------------------------------
__global__ __launch_bounds__(128) void k_prep(const float* __restrict__ th_f,
                                              const float* __restrict__ th_r,
                                              float* __restrict__ trig)
{
    int d = threadIdx.x;          // 128 threads, 1 block
    trig[d]     = cosf(th_f[d]); trig[128+d] = sinf(th_f[d]);
    trig[256+d] = cosf(th_r[d]); trig[384+d] = sinf(th_r[d]);
}

// ---------------- K1: front GEMM v2 — 128x128 tile, 8x8/thread, f32 ---------
// Grid 5120 = 1024 m-tiles (outer) x 5 n-tiles (inner). n-tile->dest:
//   nt 0,1 -> SC (silu);  nt 2 -> OM (1-sigmoid);  nt 3,4 -> GATE (silu)
// LDS: xs[32][132] + ws[32][132] f32 (33 KiB) -> 4 blocks/CU.
#define LDT 132
__global__ __launch_bounds__(256, 4) void k_front2(
    const float* __restrict__ x,
    const float* __restrict__ W_in,   const float* __restrict__ b_in,
    const float* __restrict__ W_lam,  const float* __restrict__ b_lam,
    const float* __restrict__ W_gate, const float* __restrict__ b_gate,
    u16* __restrict__ SC, u16* __restrict__ OM, u16* __restrict__ GATE)
{
    __shared__ float xs[32][LDT];   // [k][row]
    __shared__ float ws[32][LDT];   // [k][col]
    int tid = threadIdx.x;
    int bid = blockIdx.x;
    int mt = bid / 5, nt = bid % 5;
    int m0 = mt * 128;

    const float* Wsrc; int ldw, nw0; const float* bsrc;
    if (nt < 2)       { Wsrc = W_in;   ldw = 256; nw0 = nt*128;     bsrc = b_in + nt*128; }
    else if (nt == 2) { Wsrc = W_lam;  ldw = 128; nw0 = 0;          bsrc = b_lam; }
    else              { Wsrc = W_gate; ldw = 256; nw0 = (nt-3)*128; bsrc = b_gate + (nt-3)*128; }

    int ri = tid >> 4, ci = tid & 15;

    float bias[8];
    #pragma unroll
    for (int t = 0; t < 2; ++t)
    #pragma unroll
    for (int j = 0; j < 4; ++j)
        bias[t*4+j] = bsrc[t*64 + ci*4 + j];

    float acc[8][8] = {};

    for (int kc = 0; kc < 4; ++kc) {
        int k0 = kc * 32;
        __syncthreads();                 // protect prev-chunk LDS reads
        #pragma unroll
        for (int it = 0; it < 4; ++it) { // stage x: 128 rows x 32 k
            int u = it*256 + tid;
            int row = u >> 3, kq = u & 7;
            float4 v = *(const float4*)(x + (size_t)(m0+row)*128 + k0 + kq*4);
            xs[kq*4+0][row] = v.x; xs[kq*4+1][row] = v.y;
            xs[kq*4+2][row] = v.z; xs[kq*4+3][row] = v.w;
        }
        #pragma unroll
        for (int it = 0; it < 4; ++it) { // stage W: 32 k x 128 cols
            int u = it*256 + tid;
            int krow = u >> 5, c4 = u & 31;
            float4 v = *(const float4*)(Wsrc + (size_t)(k0+krow)*ldw + nw0 + c4*4);
            *(float4*)(&ws[krow][c4*4]) = v;
        }
        __syncthreads();

        #pragma unroll 2
        for (int k = 0; k < 32; ++k) {
            float4 a0 = *(const float4*)(&xs[k][ri*4]);
            float4 a1 = *(const float4*)(&xs[k][64 + ri*4]);
            float4 b0 = *(const float4*)(&ws[k][ci*4]);
            float4 b1 = *(const float4*)(&ws[k][64 + ci*4]);
            float av[8] = {a0.x,a0.y,a0.z,a0.w, a1.x,a1.y,a1.z,a1.w};
            float bv[8] = {b0.x,b0.y,b0.z,b0.w, b1.x,b1.y,b1.z,b1.w};
            #pragma unroll
            for (int rr = 0; rr < 8; ++rr)
            #pragma unroll
            for (int cc = 0; cc < 8; ++cc)
                acc[rr][cc] = fmaf(av[rr], bv[cc], acc[rr][cc]);
        }
    }

    // epilogue: activation + bf16 pack + store (8 rows x 2 col-groups of 4)
    #pragma unroll
    for (int rr = 0; rr < 8; ++rr) {
        int m = m0 + ((rr < 4) ? (ri*4 + rr) : (64 + ri*4 + rr - 4));
        #pragma unroll
        for (int t = 0; t < 2; ++t) {
            float v[4];
            #pragma unroll
            for (int j = 0; j < 4; ++j) {
                float tv = acc[rr][t*4+j] + bias[t*4+j];
                float e = __expf(-tv);
                v[j] = (nt == 2) ? e/(1.f+e) : tv/(1.f+e);
            }
            uint2 pk = make_uint2(pack2(v[0], v[1]), pack2(v[2], v[3]));
            int cl = t*64 + ci*4;
            if (nt < 2)
                *(uint2*)(&SC[(size_t)m*256 + nt*128 + cl]) = pk;
            else if (nt == 2)
                *(uint2*)(&OM[(size_t)m*128 + cl]) = pk;
            else
                *(uint2*)(&GATE[(size_t)m*256 + (nt-3)*128 + cl]) = pk;
        }
    }
}

// ---------------- K2: fused fwd+rev complex scans, full-d, bf16 I/O ----------
// One thread runs BOTH directions of one column (2 independent chains).
// FIRSTPAIR=1 (h-axis): t<64 stores hit disjoint positions; t>=64 RMW-adds
// positions this thread already wrote. FIRSTPAIR=0 (w-axis): all RMW.
template<int AXISW, int FIRSTPAIR>
__global__ __launch_bounds__(256) void k_scan2(const u16* __restrict__ SC,
                                               const u16* __restrict__ OM,
                                               const float* __restrict__ trig,
                                               u32* P)
{
    int j = blockIdx.x*256 + threadIdx.x;  // 131072 columns (full d)
    int d = j & 127;
    int col = j >> 7;                      // 0..1023
    int rowbase, stride;
    if (AXISW) { rowbase = (col>>3)*1024 + (col&7); stride = 8; }
    else       { rowbase = col;                     stride = 1024; }

    float cfF = trig[d],     sfF = trig[128+d];
    float cfR = trig[256+d], sfR = trig[384+d];

    long long rowF = rowbase;
    long long rowR = (long long)rowbase + (long long)stride*127;

    float hfr=0.f, hfi=0.f, hrr=0.f, hri=0.f;

    #define SCAN_STEP                                                     \
        u32 uF = *(const u32*)(SC + rowF*256 + 2*d);                      \
        float omF = b2f(OM[rowF*128 + d]);                                \
        u32 uR = *(const u32*)(SC + rowR*256 + 2*d);                      \
        float omR = b2f(OM[rowR*128 + d]);                                \
        float lamF = 1.f - omF, lamR = 1.f - omR;                         \
        float grF = lamF*cfF, giF = lamF*sfF;                             \
        float grR = lamR*cfR, giR = lamR*sfR;                             \
        float ieF = b2f((u16)(uF & 0xffff)), ioF = b2f((u16)(uF >> 16));  \
        float ieR = b2f((u16)(uR & 0xffff)), ioR = b2f((u16)(uR >> 16));  \
        float nfr = fmaf(grF, hfr, fmaf(-giF, hfi, omF*ieF));             \
        float nfi = fmaf(grF, hfi, fmaf( giF, hfr, omF*ioF));             \
        hfr = nfr; hfi = nfi;                                             \
        float nrr = fmaf(grR, hrr, fmaf(-giR, hri, omR*ieR));             \
        float nri = fmaf(grR, hri, fmaf( giR, hrr, omR*ioR));             \
        hrr = nrr; hri = nri;                                             \
        long long piF = rowF*128 + d;                                     \
        long long piR = rowR*128 + d;

    if (FIRSTPAIR) {
        #pragma unroll 4
        for (int t = 0; t < 64; ++t, rowF += stride, rowR -= stride) {
            SCAN_STEP
            P[piF] = pack2(hfr, hfi);
            P[piR] = pack2(hrr, hri);
        }
        #pragma unroll 4
        for (int t = 64; t < 128; ++t, rowF += stride, rowR -= stride) {
            SCAN_STEP
            u32 oF = P[piF];
            P[piF] = pack2(b2f((u16)(oF&0xffff)) + hfr, b2f((u16)(oF>>16)) + hfi);
            u32 oR = P[piR];
            P[piR] = pack2(b2f((u16)(oR&0xffff)) + hrr, b2f((u16)(oR>>16)) + hri);
        }
    } else {
        #pragma unroll 4
        for (int t = 0; t < 128; ++t, rowF += stride, rowR -= stride) {
            SCAN_STEP
            u32 oF = P[piF];
            P[piF] = pack2(b2f((u16)(oF&0xffff)) + hfr, b2f((u16)(oF>>16)) + hfi);
            u32 oR = P[piR];
            P[piR] = pack2(b2f((u16)(oR&0xffff)) + hrr, b2f((u16)(oR>>16)) + hri);
        }
    }
    #undef SCAN_STEP
}

// ---------------- K3: LN + gate + out GEMM; bf16 fgT, 4x8 tiles -------------
#define GETC(v,i) ((i)==0?(v).x:(i)==1?(v).y:(i)==2?(v).z:(v).w)
__global__ __launch_bounds__(256, 4) void k_backend_f32(
    const uint4* __restrict__ P4, const u16* __restrict__ GATE,
    const float* __restrict__ W_out, const float* __restrict__ ln_w,
    const float* __restrict__ ln_b, const float* __restrict__ bo,
    float* __restrict__ out)
{
    __shared__ u16 fgT[256][68];                // 34 KiB bf16, [channel][row]
    int tid = threadIdx.x;
    int m0 = blockIdx.x * 64;                   // 2048 blocks
    int r = tid >> 2, q = tid & 3;              // 4 threads per row
    size_t prow4 = (size_t)(m0 + r)*32 + q*8;   // uint4 units (128 u32/row)
    size_t grow = (size_t)(m0 + r)*256;         // u16 units (GATE in ws)

    uint4 ga[4], gb[4];
    #pragma unroll
    for (int g4 = 0; g4 < 4; ++g4) {
        ga[g4] = *(const uint4*)(GATE + grow + q*32 + g4*8);
        gb[g4] = *(const uint4*)(GATE + grow + 128 + q*32 + g4*8);
    }

    uint4 pw[8];                                // 32 packed complex (bf16)
    #pragma unroll
    for (int c4 = 0; c4 < 8; ++c4) pw[c4] = P4[prow4 + c4];

    float fr_[32], fi_[32];
    #pragma unroll
    for (int c4 = 0; c4 < 8; ++c4) {
        #pragma unroll
        for (int w = 0; w < 4; ++w) {
            u32 word = GETC(pw[c4], w);
            int jj = c4*4 + w;
            fr_[jj] = b2f((u16)(word & 0xffff));
            fi_[jj] = b2f((u16)(word >> 16));
        }
    }

    float sum = 0.f, ss = 0.f;
    #pragma unroll
    for (int jj = 0; jj < 32; ++jj) {
        sum += fr_[jj] + fi_[jj];
        ss  += fr_[jj]*fr_[jj] + fi_[jj]*fi_[jj];
    }
    sum += __shfl_xor(sum, 1); sum += __shfl_xor(sum, 2);
    ss  += __shfl_xor(ss, 1);  ss  += __shfl_xor(ss, 2);
    float mu = sum * (1.f/256.f);
    float var = ss * (1.f/256.f) - mu*mu;
    float rstd = rsqrtf(var + 1e-5f);

    #pragma unroll
    for (int jj = 0; jj < 32; ++jj) {
        int pd = q*32 + jj;                     // complex channel 0..127
        int g4 = jj >> 3, e = jj & 7;
        u32 gur = GETC(ga[g4], e>>1), gui = GETC(gb[g4], e>>1);
        float gvr = b2f((u16)((e&1) ? (gur>>16) : (gur&0xffff)));
        float gvi = b2f((u16)((e&1) ? (gui>>16) : (gui&0xffff)));
        float vr = ((fr_[jj] - mu)*rstd*ln_w[pd]     + ln_b[pd])     * gvr;
        float vi = ((fi_[jj] - mu)*rstd*ln_w[128+pd] + ln_b[128+pd]) * gvi;
        fgT[pd][r]     = f2b(vr);
        fgT[128+pd][r] = f2b(vi);
    }
    __syncthreads();

    // out[64][128] = fgT^T @ W_out : 4m x 8n per thread, single pass
    int ri = tid >> 4, ci = tid & 15;
    float acc[4][8] = {};
    #pragma unroll 4
    for (int k = 0; k < 256; ++k) {
        uint2 xr = *(const uint2*)(&fgT[k][ri*4]);
        float xv0 = b2f((u16)(xr.x & 0xffff));
        float xv1 = b2f((u16)(xr.x >> 16));
        float xv2 = b2f((u16)(xr.y & 0xffff));
        float xv3 = b2f((u16)(xr.y >> 16));
        const float* wrow = W_out + (size_t)k*128 + ci*8;
        float4 wv0 = *(const float4*)(wrow);
        float4 wv1 = *(const float4*)(wrow + 4);
        #define FMA8(i, xv)                                    \
            acc[i][0] = fmaf(xv, wv0.x, acc[i][0]);            \
            acc[i][1] = fmaf(xv, wv0.y, acc[i][1]);            \
            acc[i][2] = fmaf(xv, wv0.z, acc[i][2]);            \
            acc[i][3] = fmaf(xv, wv0.w, acc[i][3]);            \
            acc[i][4] = fmaf(xv, wv1.x, acc[i][4]);            \
            acc[i][5] = fmaf(xv, wv1.y, acc[i][5]);            \
            acc[i][6] = fmaf(xv, wv1.z, acc[i][6]);            \
            acc[i][7] = fmaf(xv, wv1.w, acc[i][7]);
        FMA8(0, xv0) FMA8(1, xv1) FMA8(2, xv2) FMA8(3, xv3)
        #undef FMA8
    }
    #pragma unroll
    for (int i = 0; i < 4; ++i) {
        int m = m0 + ri*4 + i;
        #pragma unroll
        for (int j = 0; j < 8; ++j) {
            int n = ci*8 + j;
            out[(size_t)m*128 + n] = acc[i][j] + bo[n];
        }
    }
}

// ---------------- launch -----------------------------------------------------
extern "C" void kernel_launch(void* const* d_in, const int* in_sizes, int n_in,
                              void* d_out, int out_size, void* d_ws, size_t ws_size,
                              hipStream_t stream)
{
    const float* x      = (const float*)d_in[0];
    const float* W_in   = (const float*)d_in[1];
    const float* b_in   = (const float*)d_in[2];
    const float* W_lam  = (const float*)d_in[3];
    const float* b_lam  = (const float*)d_in[4];
    const float* th_f   = (const float*)d_in[5];
    const float* th_r   = (const float*)d_in[6];
    const float* W_gate = (const float*)d_in[7];
    const float* b_gate = (const float*)d_in[8];
    const float* W_out  = (const float*)d_in[9];
    const float* b_out  = (const float*)d_in[10];
    const float* ln_w   = (const float*)d_in[11];
    const float* ln_b   = (const float*)d_in[12];

    // ws layout: 167,774,208 B <= proven-safe envelope
    char* ws = (char*)d_ws;
    u32* P     = (u32*)(ws);                      //  67,108,864 (bf16-pair, full d)
    u16* OM    = (u16*)(ws + 67108864LL);         //  33,554,432 (bf16 om, full d)
    u16* GATE  = (u16*)(ws + 100663296LL);        //  67,108,864 (bf16 gate)
    float* trig= (float*)(ws + 167772160LL);      //   2,048

    // d_out time-shares: SC bf16[M][256] (front->scans) -> out f32[M][128]
    u16* SC   = (u16*)d_out;
    float* out = (float*)d_out;

    hipLaunchKernelGGL(k_prep, dim3(1), dim3(128), 0, stream, th_f, th_r, trig);

    hipLaunchKernelGGL(k_front2, dim3(5120), dim3(256), 0, stream,
                       x, W_in, b_in, W_lam, b_lam, W_gate, b_gate,
                       SC, OM, GATE);

    hipLaunchKernelGGL(HIP_KERNEL_NAME(k_scan2<0,1>), dim3(512), dim3(256), 0, stream,
                       SC, OM, trig, P);
    hipLaunchKernelGGL(HIP_KERNEL_NAME(k_scan2<1,0>), dim3(512), dim3(256), 0, stream,
                       SC, OM, trig, P);

    hipLaunchKernelGGL(k_backend_f32, dim3(2048), dim3(256), 0, stream,
                       (const uint4*)P, GATE, W_out, ln_w, ln_b, b_out, out);
}

// Round 11
// 638.518 us; speedup vs baseline: 1.5662x; 1.0308x over previous
//
#include <hip/hip_runtime.h>
#include <hip/hip_bf16.h>
#include <math.h>

// Problem constants
#define HH 128
#define WWW 128
#define BB 8
#define MM (HH*WWW*BB)      // 131072 rows (h,w,b)

typedef unsigned int u32;
typedef unsigned short u16;

__device__ __forceinline__ float b2f(u16 s){ return __uint_as_float(((u32)s)<<16); }
__device__ __forceinline__ u16 f2b(float f){
    u32 u = __float_as_uint(f);
    return (u16)((u + 0x7fffu + ((u>>16)&1u)) >> 16);
}
__device__ __forceinline__ u32 pack2(float lo, float hi){
    return (u32)f2b(lo) | ((u32)f2b(hi)<<16);
}

// ---------------- K0: trig tables + W_out -> bf16 cast -----------------------
__global__ __launch_bounds__(128) void k_prep(const float* __restrict__ th_f,
                                              const float* __restrict__ th_r,
                                              const float* __restrict__ W_out,
                                              float* __restrict__ trig,
                                              u16* __restrict__ WoB)
{
    int t = blockIdx.x*128 + threadIdx.x;     // 257 blocks x 128
    if (t < 32768) {
        WoB[t] = f2b(W_out[t]);               // natural order [k][n]
    } else if (t < 32896) {
        int d = t - 32768;
        trig[d]     = cosf(th_f[d]); trig[128+d] = sinf(th_f[d]);
        trig[256+d] = cosf(th_r[d]); trig[384+d] = sinf(th_r[d]);
    }
}

// ---------------- K1: front GEMM v2 — 128x128 tile, 8x8/thread, f32 ---------
// Grid 5120 = 1024 m-tiles (outer) x 5 n-tiles (inner). n-tile->dest:
//   nt 0,1 -> SC (silu);  nt 2 -> OM (1-sigmoid);  nt 3,4 -> GATE (silu)
// LDS: xs[32][132] + ws[32][132] f32 (33 KiB) -> 4 blocks/CU.
#define LDT 132
__global__ __launch_bounds__(256, 4) void k_front2(
    const float* __restrict__ x,
    const float* __restrict__ W_in,   const float* __restrict__ b_in,
    const float* __restrict__ W_lam,  const float* __restrict__ b_lam,
    const float* __restrict__ W_gate, const float* __restrict__ b_gate,
    u16* __restrict__ SC, u16* __restrict__ OM, u16* __restrict__ GATE)
{
    __shared__ float xs[32][LDT];   // [k][row]
    __shared__ float ws[32][LDT];   // [k][col]
    int tid = threadIdx.x;
    int bid = blockIdx.x;
    int mt = bid / 5, nt = bid % 5;
    int m0 = mt * 128;

    const float* Wsrc; int ldw, nw0; const float* bsrc;
    if (nt < 2)       { Wsrc = W_in;   ldw = 256; nw0 = nt*128;     bsrc = b_in + nt*128; }
    else if (nt == 2) { Wsrc = W_lam;  ldw = 128; nw0 = 0;          bsrc = b_lam; }
    else              { Wsrc = W_gate; ldw = 256; nw0 = (nt-3)*128; bsrc = b_gate + (nt-3)*128; }

    int ri = tid >> 4, ci = tid & 15;

    float bias[8];
    #pragma unroll
    for (int t = 0; t < 2; ++t)
    #pragma unroll
    for (int j = 0; j < 4; ++j)
        bias[t*4+j] = bsrc[t*64 + ci*4 + j];

    float acc[8][8] = {};

    for (int kc = 0; kc < 4; ++kc) {
        int k0 = kc * 32;
        __syncthreads();                 // protect prev-chunk LDS reads
        #pragma unroll
        for (int it = 0; it < 4; ++it) { // stage x: 128 rows x 32 k
            int u = it*256 + tid;
            int row = u >> 3, kq = u & 7;
            float4 v = *(const float4*)(x + (size_t)(m0+row)*128 + k0 + kq*4);
            xs[kq*4+0][row] = v.x; xs[kq*4+1][row] = v.y;
            xs[kq*4+2][row] = v.z; xs[kq*4+3][row] = v.w;
        }
        #pragma unroll
        for (int it = 0; it < 4; ++it) { // stage W: 32 k x 128 cols
            int u = it*256 + tid;
            int krow = u >> 5, c4 = u & 31;
            float4 v = *(const float4*)(Wsrc + (size_t)(k0+krow)*ldw + nw0 + c4*4);
            *(float4*)(&ws[krow][c4*4]) = v;
        }
        __syncthreads();

        #pragma unroll 4
        for (int k = 0; k < 32; ++k) {
            float4 a0 = *(const float4*)(&xs[k][ri*4]);
            float4 a1 = *(const float4*)(&xs[k][64 + ri*4]);
            float4 b0 = *(const float4*)(&ws[k][ci*4]);
            float4 b1 = *(const float4*)(&ws[k][64 + ci*4]);
            #define FMA_ROW(r, av)                               \
                acc[r][0] = fmaf(av, b0.x, acc[r][0]);           \
                acc[r][1] = fmaf(av, b0.y, acc[r][1]);           \
                acc[r][2] = fmaf(av, b0.z, acc[r][2]);           \
                acc[r][3] = fmaf(av, b0.w, acc[r][3]);           \
                acc[r][4] = fmaf(av, b1.x, acc[r][4]);           \
                acc[r][5] = fmaf(av, b1.y, acc[r][5]);           \
                acc[r][6] = fmaf(av, b1.z, acc[r][6]);           \
                acc[r][7] = fmaf(av, b1.w, acc[r][7]);
            FMA_ROW(0, a0.x) FMA_ROW(1, a0.y) FMA_ROW(2, a0.z) FMA_ROW(3, a0.w)
            FMA_ROW(4, a1.x) FMA_ROW(5, a1.y) FMA_ROW(6, a1.z) FMA_ROW(7, a1.w)
            #undef FMA_ROW
        }
    }

    // epilogue: activation + bf16 pack + store (8 rows x 2 col-groups of 4)
    #pragma unroll
    for (int rr = 0; rr < 8; ++rr) {
        int m = m0 + ((rr < 4) ? (ri*4 + rr) : (64 + ri*4 + rr - 4));
        #pragma unroll
        for (int t = 0; t < 2; ++t) {
            float v[4];
            #pragma unroll
            for (int j = 0; j < 4; ++j) {
                float tv = acc[rr][t*4+j] + bias[t*4+j];
                float e = __expf(-tv);
                v[j] = (nt == 2) ? e/(1.f+e) : tv/(1.f+e);
            }
            uint2 pk = make_uint2(pack2(v[0], v[1]), pack2(v[2], v[3]));
            int cl = t*64 + ci*4;
            if (nt < 2)
                *(uint2*)(&SC[(size_t)m*256 + nt*128 + cl]) = pk;
            else if (nt == 2)
                *(uint2*)(&OM[(size_t)m*128 + cl]) = pk;
            else
                *(uint2*)(&GATE[(size_t)m*256 + (nt-3)*128 + cl]) = pk;
        }
    }
}

// ---------------- K2: fused fwd+rev complex scans, full-d, bf16 I/O ----------
template<int AXISW, int FIRSTPAIR>
__global__ __launch_bounds__(256) void k_scan2(const u16* __restrict__ SC,
                                               const u16* __restrict__ OM,
                                               const float* __restrict__ trig,
                                               u32* P)
{
    int j = blockIdx.x*256 + threadIdx.x;  // 131072 columns (full d)
    int d = j & 127;
    int col = j >> 7;                      // 0..1023
    int rowbase, stride;
    if (AXISW) { rowbase = (col>>3)*1024 + (col&7); stride = 8; }
    else       { rowbase = col;                     stride = 1024; }

    float cfF = trig[d],     sfF = trig[128+d];
    float cfR = trig[256+d], sfR = trig[384+d];

    long long rowF = rowbase;
    long long rowR = (long long)rowbase + (long long)stride*127;

    float hfr=0.f, hfi=0.f, hrr=0.f, hri=0.f;

    #define SCAN_STEP                                                     \
        u32 uF = *(const u32*)(SC + rowF*256 + 2*d);                      \
        float omF = b2f(OM[rowF*128 + d]);                                \
        u32 uR = *(const u32*)(SC + rowR*256 + 2*d);                      \
        float omR = b2f(OM[rowR*128 + d]);                                \
        float lamF = 1.f - omF, lamR = 1.f - omR;                         \
        float grF = lamF*cfF, giF = lamF*sfF;                             \
        float grR = lamR*cfR, giR = lamR*sfR;                             \
        float ieF = b2f((u16)(uF & 0xffff)), ioF = b2f((u16)(uF >> 16));  \
        float ieR = b2f((u16)(uR & 0xffff)), ioR = b2f((u16)(uR >> 16));  \
        float nfr = fmaf(grF, hfr, fmaf(-giF, hfi, omF*ieF));             \
        float nfi = fmaf(grF, hfi, fmaf( giF, hfr, omF*ioF));             \
        hfr = nfr; hfi = nfi;                                             \
        float nrr = fmaf(grR, hrr, fmaf(-giR, hri, omR*ieR));             \
        float nri = fmaf(grR, hri, fmaf( giR, hrr, omR*ioR));             \
        hrr = nrr; hri = nri;                                             \
        long long piF = rowF*128 + d;                                     \
        long long piR = rowR*128 + d;

    if (FIRSTPAIR) {
        #pragma unroll 4
        for (int t = 0; t < 64; ++t, rowF += stride, rowR -= stride) {
            SCAN_STEP
            P[piF] = pack2(hfr, hfi);
            P[piR] = pack2(hrr, hri);
        }
        #pragma unroll 4
        for (int t = 64; t < 128; ++t, rowF += stride, rowR -= stride) {
            SCAN_STEP
            u32 oF = P[piF];
            P[piF] = pack2(b2f((u16)(oF&0xffff)) + hfr, b2f((u16)(oF>>16)) + hfi);
            u32 oR = P[piR];
            P[piR] = pack2(b2f((u16)(oR&0xffff)) + hrr, b2f((u16)(oR>>16)) + hri);
        }
    } else {
        #pragma unroll 4
        for (int t = 0; t < 128; ++t, rowF += stride, rowR -= stride) {
            SCAN_STEP
            u32 oF = P[piF];
            P[piF] = pack2(b2f((u16)(oF&0xffff)) + hfr, b2f((u16)(oF>>16)) + hfi);
            u32 oR = P[piR];
            P[piR] = pack2(b2f((u16)(oR&0xffff)) + hrr, b2f((u16)(oR>>16)) + hri);
        }
    }
    #undef SCAN_STEP
}

// ---------------- K3: LN + gate + out GEMM; bf16 fgT + bf16 W, 4x8 tiles ----
#define GETC(v,i) ((i)==0?(v).x:(i)==1?(v).y:(i)==2?(v).z:(v).w)
__global__ __launch_bounds__(256, 4) void k_backend_f32(
    const uint4* __restrict__ P4, const u16* __restrict__ GATE,
    const u16* __restrict__ WoB, const float* __restrict__ ln_w,
    const float* __restrict__ ln_b, const float* __restrict__ bo,
    float* __restrict__ out)
{
    __shared__ u16 fgT[256][68];                // 34 KiB bf16, [channel][row]
    int tid = threadIdx.x;
    int m0 = blockIdx.x * 64;                   // 2048 blocks
    int r = tid >> 2, q = tid & 3;              // 4 threads per row
    size_t prow4 = (size_t)(m0 + r)*32 + q*8;   // uint4 units (128 u32/row)
    size_t grow = (size_t)(m0 + r)*256;         // u16 units (GATE in ws)

    uint4 ga[4], gb[4];
    #pragma unroll
    for (int g4 = 0; g4 < 4; ++g4) {
        ga[g4] = *(const uint4*)(GATE + grow + q*32 + g4*8);
        gb[g4] = *(const uint4*)(GATE + grow + 128 + q*32 + g4*8);
    }

    uint4 pw[8];                                // 32 packed complex (bf16)
    #pragma unroll
    for (int c4 = 0; c4 < 8; ++c4) pw[c4] = P4[prow4 + c4];

    float fr_[32], fi_[32];
    #pragma unroll
    for (int c4 = 0; c4 < 8; ++c4) {
        #pragma unroll
        for (int w = 0; w < 4; ++w) {
            u32 word = GETC(pw[c4], w);
            int jj = c4*4 + w;
            fr_[jj] = b2f((u16)(word & 0xffff));
            fi_[jj] = b2f((u16)(word >> 16));
        }
    }

    float sum = 0.f, ss = 0.f;
    #pragma unroll
    for (int jj = 0; jj < 32; ++jj) {
        sum += fr_[jj] + fi_[jj];
        ss  += fr_[jj]*fr_[jj] + fi_[jj]*fi_[jj];
    }
    sum += __shfl_xor(sum, 1); sum += __shfl_xor(sum, 2);
    ss  += __shfl_xor(ss, 1);  ss  += __shfl_xor(ss, 2);
    float mu = sum * (1.f/256.f);
    float var = ss * (1.f/256.f) - mu*mu;
    float rstd = rsqrtf(var + 1e-5f);

    #pragma unroll
    for (int jj = 0; jj < 32; ++jj) {
        int pd = q*32 + jj;                     // complex channel 0..127
        int g4 = jj >> 3, e = jj & 7;
        u32 gur = GETC(ga[g4], e>>1), gui = GETC(gb[g4], e>>1);
        float gvr = b2f((u16)((e&1) ? (gur>>16) : (gur&0xffff)));
        float gvi = b2f((u16)((e&1) ? (gui>>16) : (gui&0xffff)));
        float vr = ((fr_[jj] - mu)*rstd*ln_w[pd]     + ln_b[pd])     * gvr;
        float vi = ((fi_[jj] - mu)*rstd*ln_w[128+pd] + ln_b[128+pd]) * gvi;
        fgT[pd][r]     = f2b(vr);
        fgT[128+pd][r] = f2b(vi);
    }
    __syncthreads();

    // out[64][128] = fgT^T @ WoB : 4m x 8n per thread, single pass
    int ri = tid >> 4, ci = tid & 15;
    float acc[4][8] = {};
    #pragma unroll 4
    for (int k = 0; k < 256; ++k) {
        uint2 xr = *(const uint2*)(&fgT[k][ri*4]);
        float xv0 = b2f((u16)(xr.x & 0xffff));
        float xv1 = b2f((u16)(xr.x >> 16));
        float xv2 = b2f((u16)(xr.y & 0xffff));
        float xv3 = b2f((u16)(xr.y >> 16));
        uint4 wv = *(const uint4*)(WoB + (size_t)k*128 + ci*8);
        float w0 = b2f((u16)(wv.x & 0xffff)), w1 = b2f((u16)(wv.x >> 16));
        float w2 = b2f((u16)(wv.y & 0xffff)), w3 = b2f((u16)(wv.y >> 16));
        float w4 = b2f((u16)(wv.z & 0xffff)), w5 = b2f((u16)(wv.z >> 16));
        float w6 = b2f((u16)(wv.w & 0xffff)), w7 = b2f((u16)(wv.w >> 16));
        #define FMA8(i, xv)                                    \
            acc[i][0] = fmaf(xv, w0, acc[i][0]);               \
            acc[i][1] = fmaf(xv, w1, acc[i][1]);               \
            acc[i][2] = fmaf(xv, w2, acc[i][2]);               \
            acc[i][3] = fmaf(xv, w3, acc[i][3]);               \
            acc[i][4] = fmaf(xv, w4, acc[i][4]);               \
            acc[i][5] = fmaf(xv, w5, acc[i][5]);               \
            acc[i][6] = fmaf(xv, w6, acc[i][6]);               \
            acc[i][7] = fmaf(xv, w7, acc[i][7]);
        FMA8(0, xv0) FMA8(1, xv1) FMA8(2, xv2) FMA8(3, xv3)
        #undef FMA8
    }
    #pragma unroll
    for (int i = 0; i < 4; ++i) {
        int m = m0 + ri*4 + i;
        #pragma unroll
        for (int j = 0; j < 8; ++j) {
            int n = ci*8 + j;
            out[(size_t)m*128 + n] = acc[i][j] + bo[n];
        }
    }
}

// ---------------- launch -----------------------------------------------------
extern "C" void kernel_launch(void* const* d_in, const int* in_sizes, int n_in,
                              void* d_out, int out_size, void* d_ws, size_t ws_size,
                              hipStream_t stream)
{
    const float* x      = (const float*)d_in[0];
    const float* W_in   = (const float*)d_in[1];
    const float* b_in   = (const float*)d_in[2];
    const float* W_lam  = (const float*)d_in[3];
    const float* b_lam  = (const float*)d_in[4];
    const float* th_f   = (const float*)d_in[5];
    const float* th_r   = (const float*)d_in[6];
    const float* W_gate = (const float*)d_in[7];
    const float* b_gate = (const float*)d_in[8];
    const float* W_out  = (const float*)d_in[9];
    const float* b_out  = (const float*)d_in[10];
    const float* ln_w   = (const float*)d_in[11];
    const float* ln_b   = (const float*)d_in[12];

    // ws layout: 167,839,744 B <= 168,008,192 B proven-safe envelope
    char* ws = (char*)d_ws;
    u32* P     = (u32*)(ws);                      //  67,108,864 (bf16-pair, full d)
    u16* OM    = (u16*)(ws + 67108864LL);         //  33,554,432 (bf16 om, full d)
    u16* GATE  = (u16*)(ws + 100663296LL);        //  67,108,864 (bf16 gate)
    float* trig= (float*)(ws + 167772160LL);      //   2,048
    u16* WoB   = (u16*)(ws + 167774208LL);        //  65,536 (bf16 W_out)

    // d_out time-shares: SC bf16[M][256] (front->scans) -> out f32[M][128]
    u16* SC   = (u16*)d_out;
    float* out = (float*)d_out;

    hipLaunchKernelGGL(k_prep, dim3(257), dim3(128), 0, stream,
                       th_f, th_r, W_out, trig, WoB);

    hipLaunchKernelGGL(k_front2, dim3(5120), dim3(256), 0, stream,
                       x, W_in, b_in, W_lam, b_lam, W_gate, b_gate,
                       SC, OM, GATE);

    hipLaunchKernelGGL(HIP_KERNEL_NAME(k_scan2<0,1>), dim3(512), dim3(256), 0, stream,
                       SC, OM, trig, P);
    hipLaunchKernelGGL(HIP_KERNEL_NAME(k_scan2<1,0>), dim3(512), dim3(256), 0, stream,
                       SC, OM, trig, P);

    hipLaunchKernelGGL(k_backend_f32, dim3(2048), dim3(256), 0, stream,
                       (const uint4*)P, GATE, WoB, ln_w, ln_b, b_out, out);
}